// Round 6
// baseline (381.748 us; speedup 1.0000x reference)
//
#include <hip/hip_runtime.h>

#define HH 448
#define WW 608
#define D1 128
#define D2 128
#define D3 1024
#define HWPROD (HH*WW)          // 272384
#define CLW 164                 // conv staged cols (152 + halo + padding)

typedef __bf16 bf16x8 __attribute__((ext_vector_type(8)));
typedef float  f32x4  __attribute__((ext_vector_type(4)));

__device__ inline unsigned short f2bf(float v) {
    __bf16 b = (__bf16)v;
    return __builtin_bit_cast(unsigned short, b);
}

// 8 contiguous f32 -> bf16x8
__device__ inline bf16x8 cvt8c(const float* __restrict__ p) {
    f32x4 f0 = *reinterpret_cast<const f32x4*>(p);
    f32x4 f1 = *reinterpret_cast<const f32x4*>(p + 4);
    bf16x8 r;
    r[0]=(__bf16)f0[0]; r[1]=(__bf16)f0[1]; r[2]=(__bf16)f0[2]; r[3]=(__bf16)f0[3];
    r[4]=(__bf16)f1[0]; r[5]=(__bf16)f1[1]; r[6]=(__bf16)f1[2]; r[7]=(__bf16)f1[3];
    return r;
}

// ------------- prep: x[c][h][w] f32 -> xt[h*w][c] bf16 ------------------------
__global__ __launch_bounds__(256) void transpose_x_kernel(
    const float* __restrict__ x, unsigned short* __restrict__ xt)
{
    const int pos = blockIdx.x * 256 + threadIdx.x;
    #pragma unroll
    for (int c8 = 0; c8 < 8; ++c8) {
        bf16x8 r;
        #pragma unroll
        for (int j = 0; j < 8; ++j)
            r[j] = (__bf16)x[(size_t)(c8 * 8 + j) * HWPROD + pos];
        *reinterpret_cast<bf16x8*>(xt + (size_t)pos * 64 + c8 * 8) = r;
    }
}

// ------------- prep: w1[d][c][3][3] f32 -> w1t[tap][d][c] bf16 ----------------
__global__ __launch_bounds__(256) void convert_w1_kernel(
    const float* __restrict__ w1, unsigned short* __restrict__ w1t)
{
    const int idx = blockIdx.x * 256 + threadIdx.x;
    if (idx >= 9 * D1 * 64) return;
    const int tap = idx / (D1 * 64);
    const int rem = idx - tap * (D1 * 64);
    const int d = rem >> 6, c = rem & 63;
    w1t[idx] = f2bf(w1[(d * 64 + c) * 9 + tap]);
}

// ---------------- Stage 1: conv3x3 64->128 + b1 + lrelu -> y1[h][w][d] bf16 ----
__global__ __launch_bounds__(512) void conv_kernel(
    const unsigned short* __restrict__ xt, const unsigned short* __restrict__ w1t,
    const float* __restrict__ b1, unsigned short* __restrict__ y1)
{
    __shared__ __align__(16) unsigned char lds[3 * CLW * 128];   // 62976 B
    const int h      = blockIdx.y;
    const int wstart = blockIdx.x * 152;
    const int tid  = threadIdx.x;
    const int lane = tid & 63, wv = tid >> 6;
    const int l15 = lane & 15, lg = lane >> 4;
    const int wd = wv >> 2, wn = wv & 3;
    const int d0 = wd * 64;
    const int start = (wn < 2) ? wn * 3 : 6 + (wn - 2) * 2;   // {0,3,6,8}
    const int cnt   = (wn < 2) ? 3 : 2;

    for (int i = 0; i < 8; ++i) {
        const int s = i * 512 + tid;
        if (s < 3 * CLW * 8) {
            const int slot = s & 7;
            const int rw   = s >> 3;
            const int ri   = rw / CLW;
            const int wl   = rw - ri * CLW;
            const int hs   = h + ri - 1;
            const int gw   = wstart + wl - 1;
            uint4 val = {0u, 0u, 0u, 0u};
            if ((unsigned)hs < (unsigned)HH && (unsigned)gw < (unsigned)WW)
                val = *reinterpret_cast<const uint4*>(xt + ((size_t)hs * WW + gw) * 64 + slot * 8);
            const int dslot = slot ^ (rw & 7);
            *reinterpret_cast<uint4*>(&lds[(size_t)rw * 128 + dslot * 16]) = val;
        }
    }

    // bias into acc init
    f32x4 b1v[4];
    #pragma unroll
    for (int mf = 0; mf < 4; ++mf)
        b1v[mf] = *reinterpret_cast<const f32x4*>(b1 + d0 + mf * 16 + lg * 4);
    f32x4 acc[3][4];
    #pragma unroll
    for (int f = 0; f < 3; ++f)
        #pragma unroll
        for (int mf = 0; mf < 4; ++mf)
            acc[f][mf] = b1v[mf];

    __syncthreads();

    #pragma unroll
    for (int tap = 0; tap < 9; ++tap) {
        const int ty = tap / 3, tx = tap - ty * 3;
        bf16x8 a[4][2];
        #pragma unroll
        for (int mf = 0; mf < 4; ++mf)
            #pragma unroll
            for (int kc = 0; kc < 2; ++kc)
                a[mf][kc] = *reinterpret_cast<const bf16x8*>(
                    w1t + ((size_t)(tap * D1 + d0 + mf * 16 + l15)) * 64 + kc * 32 + lg * 8);
        #pragma unroll
        for (int f = 0; f < 3; ++f) {
            if (f < cnt) {
                const int col = (start + f) * 16 + l15;
                const int row = ty * CLW + col + tx;
                bf16x8 b[2];
                #pragma unroll
                for (int kc = 0; kc < 2; ++kc) {
                    const int sl = (kc * 4 + lg) ^ (row & 7);
                    b[kc] = *reinterpret_cast<const bf16x8*>(&lds[(size_t)row * 128 + sl * 16]);
                }
                #pragma unroll
                for (int mf = 0; mf < 4; ++mf)
                    #pragma unroll
                    for (int kc = 0; kc < 2; ++kc)
                        acc[f][mf] = __builtin_amdgcn_mfma_f32_16x16x32_bf16(
                            a[mf][kc], b[kc], acc[f][mf], 0, 0, 0);
            }
        }
    }

    #pragma unroll
    for (int f = 0; f < 3; ++f) {
        if (f < cnt) {
            const int wl = (start + f) * 16 + l15;
            if (wl < 152) {
                const int w = wstart + wl;
                #pragma unroll
                for (int mf = 0; mf < 4; ++mf) {
                    ushort4 o;
                    #pragma unroll
                    for (int r = 0; r < 4; ++r) {
                        float v = acc[f][mf][r];
                        v = fmaxf(v, 0.01f * v);
                        ((unsigned short*)&o)[r] = f2bf(v);
                    }
                    *reinterpret_cast<ushort4*>(
                        y1 + ((size_t)h * WW + w) * D1 + d0 + mf * 16 + lg * 4) = o;
                }
            }
        }
    }
}

// decode XCD-paired block id for gemm2: halves of same h -> same XCD
__device__ inline void decode_pair(int bid, int& h, int& half) {
    const int s = bid & 7, j = bid >> 3;
    half = j & 1;
    h = (j >> 1) * 8 + s;
}

// ---------------- Stage 2: y2[h][w][d] = lrelu(W2[h] @ y1[h] + b2[h]) ---------
__global__ __launch_bounds__(512) void gemm2_kernel(
    const unsigned short* __restrict__ y1, const float* __restrict__ w2,
    const float* __restrict__ b2, unsigned short* __restrict__ y2)
{
    __shared__ __align__(16) unsigned char lds[304 * 256];           // 77824 B
    int h, half;
    decode_pair(blockIdx.x, h, half);
    const int wstart = half * 304;
    const int tid = threadIdx.x;
    const int lane = tid & 63, wv = tid >> 6;
    const int l15 = lane & 15, lg = lane >> 4;
    const int e0 = wv * 16;

    {
        const unsigned char* src = reinterpret_cast<const unsigned char*>(
            y1 + ((size_t)h * WW + wstart) * D1);
        #pragma unroll
        for (int i = 0; i < 10; ++i) {
            const int c16 = i * 512 + tid;
            if (c16 < 304 * 16) {
                const int byte = c16 * 16;
                const int row  = byte >> 8;
                const int slot = (byte >> 4) & 15;
                uint4 val = *reinterpret_cast<const uint4*>(src + byte);
                *reinterpret_cast<uint4*>(&lds[row * 256 + ((slot ^ (row & 15)) << 4)]) = val;
            }
        }
    }

    bf16x8 a[4];
    #pragma unroll
    for (int kc = 0; kc < 4; ++kc)
        a[kc] = cvt8c(w2 + ((size_t)h * D2 + e0 + l15) * D1 + kc * 32 + lg * 8);
    f32x4 b2v = *reinterpret_cast<const f32x4*>(b2 + (size_t)h * D2 + e0 + lg * 4);

    int boff[4];
    #pragma unroll
    for (int kc = 0; kc < 4; ++kc)
        boff[kc] = l15 * 256 + (((kc * 4 + lg) ^ l15) << 4);

    __syncthreads();

    for (int nf = 0; nf < 19; ++nf) {
        f32x4 t = b2v;
        #pragma unroll
        for (int kc = 0; kc < 4; ++kc) {
            bf16x8 b = *reinterpret_cast<const bf16x8*>(&lds[nf * 4096 + boff[kc]]);
            t = __builtin_amdgcn_mfma_f32_16x16x32_bf16(a[kc], b, t, 0, 0, 0);
        }
        ushort4 o;
        #pragma unroll
        for (int r = 0; r < 4; ++r) {
            float v = t[r];
            v = fmaxf(v, 0.01f * v);
            ((unsigned short*)&o)[r] = f2bf(v);
        }
        *reinterpret_cast<ushort4*>(
            y2 + ((size_t)h * WW + wstart + nf * 16 + l15) * D2 + e0 + lg * 4) = o;
    }
}

// ------- Stage 3+4 fused: per (h, w-quarter); persistent pacc; final out ------
__global__ __launch_bounds__(512) void gemm3_kernel(
    const unsigned short* __restrict__ y2, const float* __restrict__ w3,
    const float* __restrict__ b3, const float* __restrict__ w4,
    const float* __restrict__ b4, float* __restrict__ out)
{
    __shared__ __align__(16) unsigned char lds[160 * 256];           // 40960 B
    int h, q;
    { const int s = blockIdx.x & 7, j = blockIdx.x >> 3; q = j & 3; h = (j >> 2) * 8 + s; }
    const int wstart = q * 160;
    const int cols = (q < 3) ? 160 : 128;
    const int nfc = cols >> 4;                      // 10 or 8
    const int tid = threadIdx.x;
    const int lane = tid & 63, wv = tid >> 6;
    const int l15 = lane & 15, lg = lane >> 4;
    const int e0 = wv * 128;

    // stage y2 quarter-panel (slot ^= row&15)
    {
        const unsigned char* src = reinterpret_cast<const unsigned char*>(
            y2 + ((size_t)h * WW + wstart) * D2);
        #pragma unroll
        for (int i = 0; i < 5; ++i) {
            const int c16 = i * 512 + tid;
            if (c16 < cols * 16) {
                const int byte = c16 * 16;
                const int row  = byte >> 8;
                const int slot = (byte >> 4) & 15;
                uint4 val = *reinterpret_cast<const uint4*>(src + byte);
                *reinterpret_cast<uint4*>(&lds[row * 256 + ((slot ^ (row & 15)) << 4)]) = val;
            }
        }
    }

    int boff[4];
    #pragma unroll
    for (int kc = 0; kc < 4; ++kc)
        boff[kc] = l15 * 256 + (((kc * 4 + lg) ^ l15) << 4);

    float pacc0[10], pacc1[10];
    #pragma unroll
    for (int i = 0; i < 10; ++i) { pacc0[i] = 0.f; pacc1[i] = 0.f; }

    __syncthreads();

    for (int ct = 0; ct < 4; ++ct) {
        const int e32 = e0 + ct * 32;
        bf16x8 a[2][4];
        #pragma unroll
        for (int mf = 0; mf < 2; ++mf)
            #pragma unroll
            for (int kc = 0; kc < 4; ++kc)
                a[mf][kc] = cvt8c(w3 + ((size_t)h * D3 + e32 + mf * 16 + l15) * D2 + kc * 32 + lg * 8);
        f32x4 b3v[2], w40[2], w41[2];
        #pragma unroll
        for (int mf = 0; mf < 2; ++mf) {
            b3v[mf] = *reinterpret_cast<const f32x4*>(b3 + (size_t)h * D3 + e32 + mf * 16 + lg * 4);
            w40[mf] = *reinterpret_cast<const f32x4*>(w4 + (size_t)h * 2 * D3 + e32 + mf * 16 + lg * 4);
            w41[mf] = *reinterpret_cast<const f32x4*>(w4 + (size_t)h * 2 * D3 + D3 + e32 + mf * 16 + lg * 4);
        }

        #pragma unroll
        for (int nf = 0; nf < 10; ++nf) {
            if (nf < nfc) {
                f32x4 t0 = b3v[0], t1 = b3v[1];
                #pragma unroll
                for (int kc = 0; kc < 4; ++kc) {
                    bf16x8 b = *reinterpret_cast<const bf16x8*>(&lds[nf * 4096 + boff[kc]]);
                    t0 = __builtin_amdgcn_mfma_f32_16x16x32_bf16(a[0][kc], b, t0, 0, 0, 0);
                    t1 = __builtin_amdgcn_mfma_f32_16x16x32_bf16(a[1][kc], b, t1, 0, 0, 0);
                }
                float p0 = 0.f, p1 = 0.f;
                #pragma unroll
                for (int r = 0; r < 4; ++r) {
                    float v0 = fmaxf(t0[r], 0.01f * t0[r]);
                    float v1 = fmaxf(t1[r], 0.01f * t1[r]);
                    p0 = fmaf(w40[0][r], v0, p0);
                    p0 = fmaf(w40[1][r], v1, p0);
                    p1 = fmaf(w41[0][r], v0, p1);
                    p1 = fmaf(w41[1][r], v1, p1);
                }
                pacc0[nf] += p0;
                pacc1[nf] += p1;
            }
        }
    }

    __syncthreads();                      // panel reads done; reuse LDS for pk
    float* pk = reinterpret_cast<float*>(lds);
    for (int i = tid; i < 2 * 160; i += 512) pk[i] = 0.f;
    __syncthreads();

    #pragma unroll
    for (int nf = 0; nf < 10; ++nf) {
        if (nf < nfc) {
            float p0 = pacc0[nf], p1 = pacc1[nf];
            p0 += __shfl_xor(p0, 16); p0 += __shfl_xor(p0, 32);
            p1 += __shfl_xor(p1, 16); p1 += __shfl_xor(p1, 32);
            if (lane < 16) {
                atomicAdd(&pk[nf * 16 + l15], p0);
                atomicAdd(&pk[160 + nf * 16 + l15], p1);
            }
        }
    }
    __syncthreads();

    const float bb0 = b4[h * 2 + 0], bb1 = b4[h * 2 + 1];
    if (tid < cols) {
        float s0 = pk[tid] + bb0;
        float s1 = pk[160 + tid] + bb1;
        out[(size_t)h * WW + wstart + tid] = s0;
        out[(size_t)HWPROD + (size_t)h * WW + wstart + tid] = fmaxf(s1, 0.01f * s1);
    }
}

extern "C" void kernel_launch(void* const* d_in, const int* in_sizes, int n_in,
                              void* d_out, int out_size, void* d_ws, size_t ws_size,
                              hipStream_t stream) {
    const float* x  = (const float*)d_in[0];
    const float* w1 = (const float*)d_in[1];
    const float* b1 = (const float*)d_in[2];
    const float* w2 = (const float*)d_in[3];
    const float* b2 = (const float*)d_in[4];
    const float* w3 = (const float*)d_in[5];
    const float* b3 = (const float*)d_in[6];
    const float* w4 = (const float*)d_in[7];
    const float* b4 = (const float*)d_in[8];
    float* out = (float*)d_out;

    char* ws = (char*)d_ws;
    size_t off = 0;
    unsigned short* y1 = (unsigned short*)(ws + off); off += (size_t)HWPROD * D1 * 2;  // 69.73 MB
    char* regionB = ws + off; off += (size_t)HWPROD * D2 * 2;
    unsigned short* xt = (unsigned short*)regionB;   // xt then y2 (disjoint lifetimes)
    unsigned short* y2 = (unsigned short*)regionB;
    unsigned short* w1t = (unsigned short*)(ws + off); off += (size_t)9 * D1 * 64 * 2;

    transpose_x_kernel<<<HWPROD / 256, 256, 0, stream>>>(x, xt);
    convert_w1_kernel<<<(9 * D1 * 64 + 255) / 256, 256, 0, stream>>>(w1, w1t);

    conv_kernel <<<dim3(4, HH), 512, 0, stream>>>(xt, w1t, b1, y1);
    gemm2_kernel<<<896, 512, 0, stream>>>(y1, w2, b2, y2);
    gemm3_kernel<<<448 * 4, 512, 0, stream>>>(y2, w3, b3, w4, b4, out);
}

// Round 7
// 361.858 us; speedup vs baseline: 1.0550x; 1.0550x over previous
//
#include <hip/hip_runtime.h>

#define HH 448
#define WW 608
#define D1 128
#define D2 128
#define D3 1024
#define HWPROD (HH*WW)          // 272384
#define CLW 164                 // conv staged cols (152 + halo + padding)

typedef __bf16 bf16x8 __attribute__((ext_vector_type(8)));
typedef float  f32x4  __attribute__((ext_vector_type(4)));
typedef _Float16 f16x4 __attribute__((ext_vector_type(4)));

__device__ inline unsigned short f2bf(float v) {
    __bf16 b = (__bf16)v;
    return __builtin_bit_cast(unsigned short, b);
}

// 8 contiguous f32 -> bf16x8
__device__ inline bf16x8 cvt8c(const float* __restrict__ p) {
    f32x4 f0 = *reinterpret_cast<const f32x4*>(p);
    f32x4 f1 = *reinterpret_cast<const f32x4*>(p + 4);
    bf16x8 r;
    r[0]=(__bf16)f0[0]; r[1]=(__bf16)f0[1]; r[2]=(__bf16)f0[2]; r[3]=(__bf16)f0[3];
    r[4]=(__bf16)f1[0]; r[5]=(__bf16)f1[1]; r[6]=(__bf16)f1[2]; r[7]=(__bf16)f1[3];
    return r;
}

// ------------- prep: x[c][h][w] f32 -> xt[h*w][c] bf16 ------------------------
__global__ __launch_bounds__(256) void transpose_x_kernel(
    const float* __restrict__ x, unsigned short* __restrict__ xt)
{
    const int pos = blockIdx.x * 256 + threadIdx.x;
    #pragma unroll
    for (int c8 = 0; c8 < 8; ++c8) {
        bf16x8 r;
        #pragma unroll
        for (int j = 0; j < 8; ++j)
            r[j] = (__bf16)x[(size_t)(c8 * 8 + j) * HWPROD + pos];
        *reinterpret_cast<bf16x8*>(xt + (size_t)pos * 64 + c8 * 8) = r;
    }
}

// ------------- prep: w1[d][c][3][3] f32 -> w1t[tap][d][c] bf16 ----------------
__global__ __launch_bounds__(256) void convert_w1_kernel(
    const float* __restrict__ w1, unsigned short* __restrict__ w1t)
{
    const int idx = blockIdx.x * 256 + threadIdx.x;
    if (idx >= 9 * D1 * 64) return;
    const int tap = idx / (D1 * 64);
    const int rem = idx - tap * (D1 * 64);
    const int d = rem >> 6, c = rem & 63;
    w1t[idx] = f2bf(w1[(d * 64 + c) * 9 + tap]);
}

// ---------------- Stage 1: conv3x3 64->128 + b1 + lrelu -> y1[h][w][d] bf16 ----
__global__ __launch_bounds__(512) void conv_kernel(
    const unsigned short* __restrict__ xt, const unsigned short* __restrict__ w1t,
    const float* __restrict__ b1, unsigned short* __restrict__ y1)
{
    __shared__ __align__(16) unsigned char lds[3 * CLW * 128];   // 62976 B
    const int h      = blockIdx.y;
    const int wstart = blockIdx.x * 152;
    const int tid  = threadIdx.x;
    const int lane = tid & 63, wv = tid >> 6;
    const int l15 = lane & 15, lg = lane >> 4;
    const int wd = wv >> 2, wn = wv & 3;
    const int d0 = wd * 64;
    const int start = (wn < 2) ? wn * 3 : 6 + (wn - 2) * 2;   // {0,3,6,8}
    const int cnt   = (wn < 2) ? 3 : 2;

    for (int i = 0; i < 8; ++i) {
        const int s = i * 512 + tid;
        if (s < 3 * CLW * 8) {
            const int slot = s & 7;
            const int rw   = s >> 3;
            const int ri   = rw / CLW;
            const int wl   = rw - ri * CLW;
            const int hs   = h + ri - 1;
            const int gw   = wstart + wl - 1;
            uint4 val = {0u, 0u, 0u, 0u};
            if ((unsigned)hs < (unsigned)HH && (unsigned)gw < (unsigned)WW)
                val = *reinterpret_cast<const uint4*>(xt + ((size_t)hs * WW + gw) * 64 + slot * 8);
            const int dslot = slot ^ (rw & 7);
            *reinterpret_cast<uint4*>(&lds[(size_t)rw * 128 + dslot * 16]) = val;
        }
    }

    f32x4 b1v[4];
    #pragma unroll
    for (int mf = 0; mf < 4; ++mf)
        b1v[mf] = *reinterpret_cast<const f32x4*>(b1 + d0 + mf * 16 + lg * 4);
    f32x4 acc[3][4];
    #pragma unroll
    for (int f = 0; f < 3; ++f)
        #pragma unroll
        for (int mf = 0; mf < 4; ++mf)
            acc[f][mf] = b1v[mf];

    __syncthreads();

    #pragma unroll
    for (int tap = 0; tap < 9; ++tap) {
        const int ty = tap / 3, tx = tap - ty * 3;
        bf16x8 a[4][2];
        #pragma unroll
        for (int mf = 0; mf < 4; ++mf)
            #pragma unroll
            for (int kc = 0; kc < 2; ++kc)
                a[mf][kc] = *reinterpret_cast<const bf16x8*>(
                    w1t + ((size_t)(tap * D1 + d0 + mf * 16 + l15)) * 64 + kc * 32 + lg * 8);
        #pragma unroll
        for (int f = 0; f < 3; ++f) {
            if (f < cnt) {
                const int col = (start + f) * 16 + l15;
                const int row = ty * CLW + col + tx;
                bf16x8 b[2];
                #pragma unroll
                for (int kc = 0; kc < 2; ++kc) {
                    const int sl = (kc * 4 + lg) ^ (row & 7);
                    b[kc] = *reinterpret_cast<const bf16x8*>(&lds[(size_t)row * 128 + sl * 16]);
                }
                #pragma unroll
                for (int mf = 0; mf < 4; ++mf)
                    #pragma unroll
                    for (int kc = 0; kc < 2; ++kc)
                        acc[f][mf] = __builtin_amdgcn_mfma_f32_16x16x32_bf16(
                            a[mf][kc], b[kc], acc[f][mf], 0, 0, 0);
            }
        }
    }

    #pragma unroll
    for (int f = 0; f < 3; ++f) {
        if (f < cnt) {
            const int wl = (start + f) * 16 + l15;
            if (wl < 152) {
                const int w = wstart + wl;
                #pragma unroll
                for (int mf = 0; mf < 4; ++mf) {
                    ushort4 o;
                    #pragma unroll
                    for (int r = 0; r < 4; ++r) {
                        float v = acc[f][mf][r];
                        v = fmaxf(v, 0.01f * v);
                        ((unsigned short*)&o)[r] = f2bf(v);
                    }
                    *reinterpret_cast<ushort4*>(
                        y1 + ((size_t)h * WW + w) * D1 + d0 + mf * 16 + lg * 4) = o;
                }
            }
        }
    }
}

// decode XCD-paired block id: halves of the same h land on the same XCD
__device__ inline void decode_pair(int bid, int& h, int& half) {
    const int s = bid & 7, j = bid >> 3;
    half = j & 1;
    h = (j >> 1) * 8 + s;
}

// ---------------- Stage 2: y2[h][w][d] = lrelu(W2[h] @ y1[h] + b2[h]) ---------
// 4 waves x 32 e-rows x 2 col-subsets: B-frag reuse R=2
__global__ __launch_bounds__(512) void gemm2_kernel(
    const unsigned short* __restrict__ y1, const float* __restrict__ w2,
    const float* __restrict__ b2, unsigned short* __restrict__ y2)
{
    __shared__ __align__(16) unsigned char lds[312 * 256];           // 79872 B
    int h, half;
    decode_pair(blockIdx.x, h, half);
    const int wstart = half * 304;
    const int tid = threadIdx.x;
    const int lane = tid & 63, wv = tid >> 6;
    const int l15 = lane & 15, lg = lane >> 4;
    const int rw = (wv & 3) * 32;                   // e-row base (0..96)
    const int cs = (wv >> 2) * 152;                 // col-subset start

    // stage y1 half-panel (304 cols of 256B, slot ^= row&15)
    {
        const unsigned char* src = reinterpret_cast<const unsigned char*>(
            y1 + ((size_t)h * WW + wstart) * D1);
        #pragma unroll
        for (int i = 0; i < 10; ++i) {
            const int c16 = i * 512 + tid;
            if (c16 < 304 * 16) {
                const int byte = c16 * 16;
                const int row  = byte >> 8;
                const int slot = (byte >> 4) & 15;
                uint4 val = *reinterpret_cast<const uint4*>(src + byte);
                *reinterpret_cast<uint4*>(&lds[row * 256 + ((slot ^ (row & 15)) << 4)]) = val;
            }
        }
    }

    bf16x8 a[2][4];
    #pragma unroll
    for (int mf = 0; mf < 2; ++mf)
        #pragma unroll
        for (int kc = 0; kc < 4; ++kc)
            a[mf][kc] = cvt8c(w2 + ((size_t)h * D2 + rw + mf * 16 + l15) * D1 + kc * 32 + lg * 8);
    f32x4 b2v[2];
    #pragma unroll
    for (int mf = 0; mf < 2; ++mf)
        b2v[mf] = *reinterpret_cast<const f32x4*>(b2 + (size_t)h * D2 + rw + mf * 16 + lg * 4);

    const int csw = (cs + l15) & 15;
    int boff[4];
    #pragma unroll
    for (int kc = 0; kc < 4; ++kc)
        boff[kc] = ((kc * 4 + lg) ^ csw) << 4;

    __syncthreads();

    for (int nf = 0; nf < 10; ++nf) {
        const int col = cs + nf * 16 + l15;         // 0..311
        bf16x8 b[4];
        #pragma unroll
        for (int kc = 0; kc < 4; ++kc)
            b[kc] = *reinterpret_cast<const bf16x8*>(&lds[col * 256 + boff[kc]]);
        f32x4 t[2] = {b2v[0], b2v[1]};
        #pragma unroll
        for (int kc = 0; kc < 4; ++kc) {
            t[0] = __builtin_amdgcn_mfma_f32_16x16x32_bf16(a[0][kc], b[kc], t[0], 0, 0, 0);
            t[1] = __builtin_amdgcn_mfma_f32_16x16x32_bf16(a[1][kc], b[kc], t[1], 0, 0, 0);
        }
        if (col < cs + 152) {
            #pragma unroll
            for (int mf = 0; mf < 2; ++mf) {
                ushort4 o;
                #pragma unroll
                for (int r = 0; r < 4; ++r) {
                    float v = t[mf][r];
                    v = fmaxf(v, 0.01f * v);
                    ((unsigned short*)&o)[r] = f2bf(v);
                }
                *reinterpret_cast<ushort4*>(
                    y2 + ((size_t)h * WW + wstart + col) * D2 + rw + mf * 16 + lg * 4) = o;
            }
        }
    }
}

// ------- Stage 3+4 fused: per (h, col-half); e-chunks of 64 (R=4); MFMA fold --
__global__ __launch_bounds__(512) void gemm3_kernel(
    const unsigned short* __restrict__ y2, const float* __restrict__ w3,
    const float* __restrict__ b3, const float* __restrict__ w4,
    const float* __restrict__ b4, float* __restrict__ out)
{
    __shared__ __align__(16) unsigned char lds[304 * 256 + 2 * 304 * 4]; // 80256 B
    float* pk = reinterpret_cast<float*>(&lds[304 * 256]);               // pk[2][304]
    int h, half;
    decode_pair(blockIdx.x, h, half);
    const int wstart = half * 304;
    const int tid = threadIdx.x;
    const int lane = tid & 63, wv = tid >> 6;
    const int l15 = lane & 15, lg = lane >> 4;
    const int e0 = wv * 128;

    for (int i = tid; i < 2 * 304; i += 512) pk[i] = 0.f;

    // stage y2 half-panel (slot ^= row&15)
    {
        const unsigned char* src = reinterpret_cast<const unsigned char*>(
            y2 + ((size_t)h * WW + wstart) * D2);
        #pragma unroll
        for (int i = 0; i < 10; ++i) {
            const int c16 = i * 512 + tid;
            if (c16 < 304 * 16) {
                const int byte = c16 * 16;
                const int row  = byte >> 8;
                const int slot = (byte >> 4) & 15;
                uint4 val = *reinterpret_cast<const uint4*>(src + byte);
                *reinterpret_cast<uint4*>(&lds[row * 256 + ((slot ^ (row & 15)) << 4)]) = val;
            }
        }
    }

    int boff[4];
    #pragma unroll
    for (int kc = 0; kc < 4; ++kc)
        boff[kc] = l15 * 256 + (((kc * 4 + lg) ^ l15) << 4);

    // ---- ct0 A-frags, bias, w4-fold frags loaded BEFORE the barrier ----
    bf16x8 a[4][4];
    f32x4 b3v[4];
    f16x4 af[4];
    {
        const int e64 = e0;
        #pragma unroll
        for (int mf = 0; mf < 4; ++mf) {
            #pragma unroll
            for (int kc = 0; kc < 4; ++kc)
                a[mf][kc] = cvt8c(w3 + ((size_t)h * D3 + e64 + mf * 16 + l15) * D2 + kc * 32 + lg * 8);
            b3v[mf] = *reinterpret_cast<const f32x4*>(b3 + (size_t)h * D3 + e64 + mf * 16 + lg * 4);
            f16x4 z = {(_Float16)0.f, (_Float16)0.f, (_Float16)0.f, (_Float16)0.f};
            if (l15 < 2) {
                f32x4 wv4 = *reinterpret_cast<const f32x4*>(
                    w4 + (size_t)h * 2 * D3 + (size_t)l15 * D3 + e64 + mf * 16 + lg * 4);
                #pragma unroll
                for (int j = 0; j < 4; ++j) z[j] = (_Float16)wv4[j];
            }
            af[mf] = z;
        }
    }

    __syncthreads();

    #pragma unroll 1
    for (int ct = 0; ct < 2; ++ct) {
        if (ct == 1) {
            const int e64 = e0 + 64;
            #pragma unroll
            for (int mf = 0; mf < 4; ++mf) {
                #pragma unroll
                for (int kc = 0; kc < 4; ++kc)
                    a[mf][kc] = cvt8c(w3 + ((size_t)h * D3 + e64 + mf * 16 + l15) * D2 + kc * 32 + lg * 8);
                b3v[mf] = *reinterpret_cast<const f32x4*>(b3 + (size_t)h * D3 + e64 + mf * 16 + lg * 4);
                f16x4 z = {(_Float16)0.f, (_Float16)0.f, (_Float16)0.f, (_Float16)0.f};
                if (l15 < 2) {
                    f32x4 wv4 = *reinterpret_cast<const f32x4*>(
                        w4 + (size_t)h * 2 * D3 + (size_t)l15 * D3 + e64 + mf * 16 + lg * 4);
                    #pragma unroll
                    for (int j = 0; j < 4; ++j) z[j] = (_Float16)wv4[j];
                }
                af[mf] = z;
            }
        }

        for (int nf = 0; nf < 19; ++nf) {
            bf16x8 b[4];
            #pragma unroll
            for (int kc = 0; kc < 4; ++kc)
                b[kc] = *reinterpret_cast<const bf16x8*>(&lds[nf * 4096 + boff[kc]]);
            f32x4 t[4] = {b3v[0], b3v[1], b3v[2], b3v[3]};
            #pragma unroll
            for (int kc = 0; kc < 4; ++kc)
                #pragma unroll
                for (int mf = 0; mf < 4; ++mf)
                    t[mf] = __builtin_amdgcn_mfma_f32_16x16x32_bf16(a[mf][kc], b[kc], t[mf], 0, 0, 0);

            // w4-fold via MFMA: P[k,col] += sum_e w4[k,e]*lrelu(y3[e,col])
            f32x4 pacc = {};
            #pragma unroll
            for (int mf = 0; mf < 4; ++mf) {
                f16x4 vb;
                #pragma unroll
                for (int r = 0; r < 4; ++r) {
                    float v = fmaxf(t[mf][r], 0.01f * t[mf][r]);
                    vb[r] = (_Float16)v;
                }
                pacc = __builtin_amdgcn_mfma_f32_16x16x16f16(af[mf], vb, pacc, 0, 0, 0);
            }
            if (lg == 0) {
                atomicAdd(&pk[nf * 16 + l15], pacc[0]);
                atomicAdd(&pk[304 + nf * 16 + l15], pacc[1]);
            }
        }
    }
    __syncthreads();

    const float bb0 = b4[h * 2 + 0], bb1 = b4[h * 2 + 1];
    if (tid < 304) {
        float s0 = pk[tid] + bb0;
        float s1 = pk[304 + tid] + bb1;
        out[(size_t)h * WW + wstart + tid] = s0;
        out[(size_t)HWPROD + (size_t)h * WW + wstart + tid] = fmaxf(s1, 0.01f * s1);
    }
}

extern "C" void kernel_launch(void* const* d_in, const int* in_sizes, int n_in,
                              void* d_out, int out_size, void* d_ws, size_t ws_size,
                              hipStream_t stream) {
    const float* x  = (const float*)d_in[0];
    const float* w1 = (const float*)d_in[1];
    const float* b1 = (const float*)d_in[2];
    const float* w2 = (const float*)d_in[3];
    const float* b2 = (const float*)d_in[4];
    const float* w3 = (const float*)d_in[5];
    const float* b3 = (const float*)d_in[6];
    const float* w4 = (const float*)d_in[7];
    const float* b4 = (const float*)d_in[8];
    float* out = (float*)d_out;

    char* ws = (char*)d_ws;
    size_t off = 0;
    unsigned short* y1 = (unsigned short*)(ws + off); off += (size_t)HWPROD * D1 * 2;  // 69.73 MB
    char* regionB = ws + off; off += (size_t)HWPROD * D2 * 2;
    unsigned short* xt = (unsigned short*)regionB;   // xt then y2 (disjoint lifetimes)
    unsigned short* y2 = (unsigned short*)regionB;
    unsigned short* w1t = (unsigned short*)(ws + off); off += (size_t)9 * D1 * 64 * 2;

    transpose_x_kernel<<<HWPROD / 256, 256, 0, stream>>>(x, xt);
    convert_w1_kernel<<<(9 * D1 * 64 + 255) / 256, 256, 0, stream>>>(w1, w1t);

    conv_kernel <<<dim3(4, HH), 512, 0, stream>>>(xt, w1t, b1, y1);
    gemm2_kernel<<<896, 512, 0, stream>>>(y1, w2, b2, y2);
    gemm3_kernel<<<896, 512, 0, stream>>>(y2, w3, b3, w4, b4, out);
}